// Round 6
// baseline (66.477 us; speedup 1.0000x reference)
//
#include <hip/hip_runtime.h>

// Problem constants (from reference setup_inputs)
static constexpr int kA = 128;   // atoms
static constexpr int kN = 64;    // neighbors
static constexpr int kG = 16;    // grid size per axis
static constexpr int kC = 10;    // channels = 5 types x 2 grid lengths

// out[b=0][a][c][x][y][z], c = type_idx*2 + length_idx
// Per channel (Z, L):
//   out = sum_{n: Z_n == Z} exp(coeff*||g - d_n||^2) + (N - cnt_Z) * exp(coeff*|g|^2)
// (reference masks d, not the exp). Separable: exp = ex*ey*ez.
//
// Round-6: LDS-free, barrier-free. R5 was prologue-latency bound (global load
// -> 3072 staged exps -> ds_write -> __syncthreads chain per block). With only
// ~3.8 matched neighbors/channel, direct evaluation is cheaper: per matched n
// (wave-uniform, iterated from the __ballot mask in SGPRs), broadcast d_n via
// 3 __shfl and evaluate 9 exps + 16 FMAs per thread. No LDS, no barrier, all
// loop iterations independent; LDS=0 -> 8 blocks/CU resident (wave-limited),
// overlapping per-block load latency.
//
// Ownership (fully-coalesced stores): float4 #(t+256q) of the channel =
// (x = t>>6 + 4q, y = (t>>2)&15, z = 4*(t&3)..+3); per store instruction a
// wave writes contiguous 1 KB (full 64 B lines).

__global__ __launch_bounds__(256) void voxel_kernel(
    const float* __restrict__ dvec,   // (1, A, N, 3) fp32
    const float* __restrict__ sigma,  // (1,) fp32
    const int*   __restrict__ zn,     // (A, N) int32
    float*       __restrict__ out)    // (1, A, 10, G, G, G) fp32
{
    const int blk = blockIdx.x;          // a*10 + c,  c = ch*2 + li
    const int a   = blk / 10;
    const int c   = blk - a * 10;
    const int ch  = c >> 1;
    const int li  = c & 1;

    const int Ztab[5] = {1, 6, 7, 8, 16};
    const int Ztarget = Ztab[ch];

    const float Lg   = li ? 12.0f : 8.0f;
    const float step = Lg * (1.0f / 15.0f);
    const float t0   = -0.5f * Lg;
    const float sg   = sigma[0];
    const float coeff = -0.5f / (sg * sg);

    const int t    = threadIdx.x;        // 0..255
    const int lane = t & 63;

    // --- Per-lane neighbor data: lane l holds zn and d for neighbor l.
    //     (Each wave reads the same 1 KB region — coalesced, L1/L2-served.)
    const int   Zl  = zn[a * kN + lane];
    const float* dl = dvec + ((size_t)a * kN + lane) * 3;
    const float dxl = dl[0];
    const float dyl = dl[1];
    const float dzl = dl[2];

    unsigned long long mask = __ballot(Zl == Ztarget);  // wave-uniform
    const int cnt = __popcll(mask);

    // Grid coordinates owned by this thread (see ownership mapping above).
    const int y  = (t >> 2) & 15;
    const int zq = (t & 3) * 4;
    const int xb = t >> 6;               // x_i = xb + 4i
    const float gy = t0 + y * step;
    float gxv[4], gzv[4];
#pragma unroll
    for (int i = 0; i < 4; ++i) gxv[i] = t0 + (xb + 4 * i) * step;
#pragma unroll
    for (int j = 0; j < 4; ++j) gzv[j] = t0 + (zq + j) * step;

    // --- Origin-centered term: (kN - cnt) non-matching neighbors.
    float acc[4][4];
    {
        const float w  = (float)(kN - cnt);
        const float ey0 = __expf(coeff * gy * gy);
        float ex0[4], ez0[4];
#pragma unroll
        for (int i = 0; i < 4; ++i) ex0[i] = __expf(coeff * gxv[i] * gxv[i]);
#pragma unroll
        for (int j = 0; j < 4; ++j) ez0[j] = __expf(coeff * gzv[j] * gzv[j]);
#pragma unroll
        for (int i = 0; i < 4; ++i) {
            const float wx = w * ey0 * ex0[i];
#pragma unroll
            for (int j = 0; j < 4; ++j)
                acc[i][j] = wx * ez0[j];
        }
    }

    // --- Matched neighbors: broadcast d_n via shuffles, evaluate directly.
    while (mask) {
        const int n = (int)__builtin_ctzll(mask);   // wave-uniform
        mask &= mask - 1ull;
        const float dx = __shfl(dxl, n);
        const float dy = __shfl(dyl, n);
        const float dz = __shfl(dzl, n);

        const float ry = gy - dy;
        const float py = __expf(coeff * ry * ry);
        float ex[4], ez[4];
#pragma unroll
        for (int i = 0; i < 4; ++i) {
            const float rx = gxv[i] - dx;
            ex[i] = __expf(coeff * rx * rx);
        }
#pragma unroll
        for (int j = 0; j < 4; ++j) {
            const float rz = gzv[j] - dz;
            ez[j] = __expf(coeff * rz * rz);
        }
#pragma unroll
        for (int i = 0; i < 4; ++i) {
            const float pxy = ex[i] * py;
#pragma unroll
            for (int j = 0; j < 4; ++j)
                acc[i][j] = fmaf(pxy, ez[j], acc[i][j]);
        }
    }

    // --- Fully-coalesced store: per instruction q, a wave writes contiguous
    //     1 KB (float4 #(wave*64 + lane + 256q)).
    float4* o = (float4*)(out + ((size_t)a * kC + c) * (kG * kG * kG));
#pragma unroll
    for (int q = 0; q < 4; ++q)
        o[t + 256 * q] = make_float4(acc[q][0], acc[q][1], acc[q][2], acc[q][3]);
}

extern "C" void kernel_launch(void* const* d_in, const int* in_sizes, int n_in,
                              void* d_out, int out_size, void* d_ws, size_t ws_size,
                              hipStream_t stream) {
    const float* dvec  = (const float*)d_in[0];   // distance_vector (1,128,64,3) fp32
    const float* sigma = (const float*)d_in[1];   // sigma (1,) fp32
    const int*   zn    = (const int*)d_in[2];     // atomic_numbers (128,64) int32
    float* out = (float*)d_out;                   // (1,128,10,16,16,16) fp32

    voxel_kernel<<<dim3(kA * kC), dim3(256), 0, stream>>>(dvec, sigma, zn, out);
}